// Round 1
// baseline (734.742 us; speedup 1.0000x reference)
//
#include <hip/hip_runtime.h>
#include <math.h>

#define N_NODES 50000
#define N_EDGES 800000
#define IN_F 768
#define HID 128
#define CLS 40
#define EPS 1e-5f

// ---------------- degree / normalization ----------------

__global__ void k_deg(const int* __restrict__ src, const int* __restrict__ dst,
                      int* __restrict__ deg_out, int* __restrict__ deg_in) {
    int e = blockIdx.x * 256 + threadIdx.x;
    if (e < N_EDGES) {
        atomicAdd(&deg_out[src[e]], 1);
        atomicAdd(&deg_in[dst[e]], 1);
    }
}

__global__ void k_rsqrt(const int* __restrict__ deg_out, const int* __restrict__ deg_in,
                        float* __restrict__ do_is, float* __restrict__ di_is) {
    int i = blockIdx.x * 256 + threadIdx.x;
    if (i < N_NODES) {
        do_is[i] = rsqrtf((float)max(deg_out[i], 1));
        di_is[i] = rsqrtf((float)max(deg_in[i], 1));
    }
}

// ---------------- CSR build: scan + fill ----------------

__global__ void k_scanA(const int* __restrict__ deg_in, int* __restrict__ tmp,
                        int* __restrict__ bsum) {
    __shared__ int s[256];
    int t = threadIdx.x;
    int i = blockIdx.x * 256 + t;
    int v = (i < N_NODES) ? deg_in[i] : 0;
    s[t] = v;
    __syncthreads();
    for (int off = 1; off < 256; off <<= 1) {
        int x = 0;
        if (t >= off) x = s[t - off];
        __syncthreads();
        if (t >= off) s[t] += x;
        __syncthreads();
    }
    if (i < N_NODES) tmp[i] = s[t];
    if (t == 255) bsum[blockIdx.x] = s[255];
}

__global__ void k_scanB(const int* __restrict__ bsum, int* __restrict__ boff, int nb) {
    if (threadIdx.x == 0 && blockIdx.x == 0) {
        int run = 0;
        for (int b = 0; b < nb; b++) { boff[b] = run; run += bsum[b]; }
    }
}

__global__ void k_scanC(const int* __restrict__ tmp, const int* __restrict__ deg_in,
                        const int* __restrict__ boff, int* __restrict__ row_ptr) {
    int i = blockIdx.x * 256 + threadIdx.x;
    if (i < N_NODES) row_ptr[i] = tmp[i] - deg_in[i] + boff[blockIdx.x];
    if (i == 0) row_ptr[N_NODES] = N_EDGES;
}

__global__ void k_fill(const int* __restrict__ src, const int* __restrict__ dst,
                       const int* __restrict__ row_ptr, int* __restrict__ cnt,
                       int* __restrict__ col) {
    int e = blockIdx.x * 256 + threadIdx.x;
    if (e < N_EDGES) {
        int d = dst[e];
        int pos = row_ptr[d] + atomicAdd(&cnt[d], 1);
        col[pos] = src[e];
    }
}

// ---------------- LN stats over input features (768) ----------------

__global__ void k_lnstats(const float* __restrict__ feat, float* __restrict__ mu,
                          float* __restrict__ rstd) {
    __shared__ float ss[256], sq[256];
    int row = blockIdx.x;
    int t = threadIdx.x;
    const float* x = feat + (size_t)row * IN_F;
    float s = 0.f, q = 0.f;
    for (int k = t; k < IN_F; k += 256) {
        float v = x[k];
        s += v;
        q += v * v;
    }
    ss[t] = s; sq[t] = q;
    __syncthreads();
    for (int off = 128; off > 0; off >>= 1) {
        if (t < off) { ss[t] += ss[t + off]; sq[t] += sq[t + off]; }
        __syncthreads();
    }
    if (t == 0) {
        float m = ss[0] / (float)IN_F;
        float var = sq[0] / (float)IN_F - m * m;
        mu[row] = m;
        rstd[row] = rsqrtf(var + EPS);
    }
}

// ---------------- GEMM1: out = (LN(feat)@W0) * do_is[row]  [M,768]x[768,128] ----------------

__global__ void k_gemm1(const float* __restrict__ feat, const float* __restrict__ W0,
                        const float* __restrict__ g, const float* __restrict__ b,
                        const float* __restrict__ mu, const float* __restrict__ rstd,
                        const float* __restrict__ do_is, float* __restrict__ out) {
    __shared__ float As[16][64];
    __shared__ float Bs[16][128];
    int t = threadIdx.x;
    int row0 = blockIdx.x * 64;
    int r8 = (t >> 5) * 8;
    int c4 = (t & 31) * 4;
    float acc[8][4] = {};
    for (int k0 = 0; k0 < IN_F; k0 += 16) {
        for (int i = 0; i < 4; i++) {
            int idx = t + i * 256;
            int kk = idx & 15, m = idx >> 4;
            int row = row0 + m, k = k0 + kk;
            float v = 0.f;
            if (row < N_NODES) {
                float x = feat[(size_t)row * IN_F + k];
                v = (x - mu[row]) * rstd[row] * g[k] + b[k];
            }
            As[kk][m] = v;
        }
        for (int i = 0; i < 8; i++) {
            int idx = t + i * 256;
            int c = idx & 127, kk = idx >> 7;
            Bs[kk][c] = W0[(size_t)(k0 + kk) * HID + c];
        }
        __syncthreads();
        for (int kk = 0; kk < 16; kk++) {
            float bb[4];
            for (int c = 0; c < 4; c++) bb[c] = Bs[kk][c4 + c];
            for (int r = 0; r < 8; r++) {
                float a = As[kk][r8 + r];
                for (int c = 0; c < 4; c++) acc[r][c] = fmaf(a, bb[c], acc[r][c]);
            }
        }
        __syncthreads();
    }
    for (int r = 0; r < 8; r++) {
        int row = row0 + r8 + r;
        if (row < N_NODES) {
            float s = do_is[row];
            for (int c = 0; c < 4; c++) out[(size_t)row * HID + c4 + c] = acc[r][c] * s;
        }
    }
}

// ---------------- GEMM2: out = (A@W1) * di_is[row]  [M,128]x[128,128] ----------------

__global__ void k_gemm2(const float* __restrict__ A, const float* __restrict__ W,
                        const float* __restrict__ di_is, float* __restrict__ out) {
    __shared__ float As[16][64];
    __shared__ float Bs[16][128];
    int t = threadIdx.x;
    int row0 = blockIdx.x * 64;
    int r8 = (t >> 5) * 8;
    int c4 = (t & 31) * 4;
    float acc[8][4] = {};
    for (int k0 = 0; k0 < HID; k0 += 16) {
        for (int i = 0; i < 4; i++) {
            int idx = t + i * 256;
            int kk = idx & 15, m = idx >> 4;
            int row = row0 + m;
            As[kk][m] = (row < N_NODES) ? A[(size_t)row * HID + k0 + kk] : 0.f;
        }
        for (int i = 0; i < 8; i++) {
            int idx = t + i * 256;
            int c = idx & 127, kk = idx >> 7;
            Bs[kk][c] = W[(size_t)(k0 + kk) * HID + c];
        }
        __syncthreads();
        for (int kk = 0; kk < 16; kk++) {
            float bb[4];
            for (int c = 0; c < 4; c++) bb[c] = Bs[kk][c4 + c];
            for (int r = 0; r < 8; r++) {
                float a = As[kk][r8 + r];
                for (int c = 0; c < 4; c++) acc[r][c] = fmaf(a, bb[c], acc[r][c]);
            }
        }
        __syncthreads();
    }
    for (int r = 0; r < 8; r++) {
        int row = row0 + r8 + r;
        if (row < N_NODES) {
            float s = di_is[row];
            for (int c = 0; c < 4; c++) out[(size_t)row * HID + c4 + c] = acc[r][c] * s;
        }
    }
}

// ---------------- GEMM3: out = A@W2  [M,128]x[128,40] ----------------

__global__ void k_gemm3(const float* __restrict__ A, const float* __restrict__ W,
                        float* __restrict__ out) {
    __shared__ float As[16][64];
    __shared__ float Bs[16][40];
    int t = threadIdx.x;
    int row0 = blockIdx.x * 64;
    int r = t >> 2;
    int c0 = (t & 3) * 10;
    float acc[10] = {};
    for (int k0 = 0; k0 < HID; k0 += 16) {
        for (int i = 0; i < 4; i++) {
            int idx = t + i * 256;
            int kk = idx & 15, m = idx >> 4;
            int row = row0 + m;
            As[kk][m] = (row < N_NODES) ? A[(size_t)row * HID + k0 + kk] : 0.f;
        }
        for (int i = 0; i < 3; i++) {
            int idx = t + i * 256;
            if (idx < 16 * CLS) {
                int c = idx % CLS, kk = idx / CLS;
                Bs[kk][c] = W[(size_t)(k0 + kk) * CLS + c];
            }
        }
        __syncthreads();
        for (int kk = 0; kk < 16; kk++) {
            float a = As[kk][r];
            for (int c = 0; c < 10; c++) acc[c] = fmaf(a, Bs[kk][c0 + c], acc[c]);
        }
        __syncthreads();
    }
    int row = row0 + r;
    if (row < N_NODES) {
        for (int c = 0; c < 10; c++) out[(size_t)row * CLS + c0 + c] = acc[c];
    }
}

// ---------------- CSR aggregation, 128 features (wave per node) ----------------

__global__ void k_agg128(const float* __restrict__ h, const int* __restrict__ row_ptr,
                         const int* __restrict__ col, const float* __restrict__ scale,
                         float* __restrict__ out) {
    int wid = (blockIdx.x * blockDim.x + threadIdx.x) >> 6;
    int lane = threadIdx.x & 63;
    if (wid >= N_NODES) return;
    int s = row_ptr[wid], e = row_ptr[wid + 1];
    const float2* h2 = (const float2*)h;
    float2 acc = make_float2(0.f, 0.f);
    for (int i = s; i < e; i++) {
        int sn = col[i];
        float2 v = h2[(size_t)sn * 64 + lane];
        acc.x += v.x;
        acc.y += v.y;
    }
    float sc = scale ? scale[wid] : 1.f;
    ((float2*)out)[(size_t)wid * 64 + lane] = make_float2(acc.x * sc, acc.y * sc);
}

// ---------------- CSR aggregation, 40 features + bias (wave per node) ----------------

__global__ void k_agg40(const float* __restrict__ h, const int* __restrict__ row_ptr,
                        const int* __restrict__ col, const float* __restrict__ di_is,
                        const float* __restrict__ b2, float* __restrict__ out) {
    int wid = (blockIdx.x * blockDim.x + threadIdx.x) >> 6;
    int lane = threadIdx.x & 63;
    if (wid >= N_NODES) return;
    if (lane < CLS) {
        int s = row_ptr[wid], e = row_ptr[wid + 1];
        float acc = 0.f;
        for (int i = s; i < e; i++) acc += h[(size_t)col[i] * CLS + lane];
        out[(size_t)wid * CLS + lane] = acc * di_is[wid] + b2[lane];
    }
}

// ---------------- LN(128) + ReLU + x do_is (wave per row) ----------------

__global__ void k_ln128(const float* __restrict__ in, const float* __restrict__ g,
                        const float* __restrict__ b, const float* __restrict__ do_is,
                        float* __restrict__ out) {
    int wid = (blockIdx.x * blockDim.x + threadIdx.x) >> 6;
    int lane = threadIdx.x & 63;
    if (wid >= N_NODES) return;
    const float2* in2 = (const float2*)in;
    float2 v = in2[(size_t)wid * 64 + lane];
    float s = v.x + v.y;
    float q = v.x * v.x + v.y * v.y;
    for (int m = 1; m < 64; m <<= 1) {
        s += __shfl_xor(s, m);
        q += __shfl_xor(q, m);
    }
    float mu = s * (1.f / 128.f);
    float var = q * (1.f / 128.f) - mu * mu;
    float rstd = rsqrtf(var + EPS);
    float2 gg = ((const float2*)g)[lane];
    float2 bb = ((const float2*)b)[lane];
    float sc = do_is[wid];
    float y0 = fmaxf((v.x - mu) * rstd * gg.x + bb.x, 0.f) * sc;
    float y1 = fmaxf((v.y - mu) * rstd * gg.y + bb.y, 0.f) * sc;
    ((float2*)out)[(size_t)wid * 64 + lane] = make_float2(y0, y1);
}

// ---------------- launch ----------------

extern "C" void kernel_launch(void* const* d_in, const int* in_sizes, int n_in,
                              void* d_out, int out_size, void* d_ws, size_t ws_size,
                              hipStream_t stream) {
    (void)in_sizes; (void)n_in; (void)out_size; (void)ws_size;
    const float* feat = (const float*)d_in[0];
    const int*   src  = (const int*)d_in[1];
    const int*   dst  = (const int*)d_in[2];
    const float* W0   = (const float*)d_in[3];
    const float* W1   = (const float*)d_in[4];
    const float* W2   = (const float*)d_in[5];
    const float* b2   = (const float*)d_in[6];
    const float* g_in = (const float*)d_in[7];
    const float* b_in = (const float*)d_in[8];
    const float* g0   = (const float*)d_in[9];
    const float* b0   = (const float*)d_in[10];
    const float* g1   = (const float*)d_in[11];
    const float* b1   = (const float*)d_in[12];
    float* out = (float*)d_out;

    char* w = (char*)d_ws;
    size_t off = 0;
    auto take = [&](size_t bytes) -> void* {
        void* p = w + off;
        off += (bytes + 255) & ~(size_t)255;
        return p;
    };
    int*   deg_out_i = (int*)take((size_t)N_NODES * 4);
    int*   deg_in_i  = (int*)take((size_t)N_NODES * 4);
    float* do_is     = (float*)take((size_t)N_NODES * 4);
    float* di_is     = (float*)take((size_t)N_NODES * 4);
    int*   tmp       = (int*)take((size_t)N_NODES * 4);
    int*   bsum      = (int*)take(256 * 4);
    int*   boff      = (int*)take(256 * 4);
    int*   row_ptr   = (int*)take((size_t)(N_NODES + 1) * 4);
    int*   cnt       = (int*)take((size_t)N_NODES * 4);
    int*   col       = (int*)take((size_t)N_EDGES * 4);
    float* mu        = (float*)take((size_t)N_NODES * 4);
    float* rstd      = (float*)take((size_t)N_NODES * 4);
    float* h_a       = (float*)take((size_t)N_NODES * HID * 4);
    float* h_b       = (float*)take((size_t)N_NODES * HID * 4);
    float* h_c       = (float*)take((size_t)N_NODES * CLS * 4);

    const int NB_E = (N_EDGES + 255) / 256;        // 3125
    const int NB_N = (N_NODES + 255) / 256;        // 196
    const int NB_M64 = (N_NODES + 63) / 64;        // 782
    const int NB_WAVE = (N_NODES * 64 + 255) / 256; // 12500

    hipMemsetAsync(deg_out_i, 0, (size_t)N_NODES * 4, stream);
    hipMemsetAsync(deg_in_i, 0, (size_t)N_NODES * 4, stream);
    hipMemsetAsync(cnt, 0, (size_t)N_NODES * 4, stream);

    k_deg<<<NB_E, 256, 0, stream>>>(src, dst, deg_out_i, deg_in_i);
    k_rsqrt<<<NB_N, 256, 0, stream>>>(deg_out_i, deg_in_i, do_is, di_is);

    k_scanA<<<NB_N, 256, 0, stream>>>(deg_in_i, tmp, bsum);
    k_scanB<<<1, 1, 0, stream>>>(bsum, boff, NB_N);
    k_scanC<<<NB_N, 256, 0, stream>>>(tmp, deg_in_i, boff, row_ptr);
    k_fill<<<NB_E, 256, 0, stream>>>(src, dst, row_ptr, cnt, col);

    k_lnstats<<<N_NODES, 256, 0, stream>>>(feat, mu, rstd);

    // Layer 0: h_a = (LN(feat)@W0)*do_is ; h_b = agg(h_a)*di_is ; h_a = relu(LN(h_b))*do_is
    k_gemm1<<<NB_M64, 256, 0, stream>>>(feat, W0, g_in, b_in, mu, rstd, do_is, h_a);
    k_agg128<<<NB_WAVE, 256, 0, stream>>>(h_a, row_ptr, col, di_is, h_b);
    k_ln128<<<NB_WAVE, 256, 0, stream>>>(h_b, g0, b0, do_is, h_a);

    // Layer 1: h_b = agg(h_a) ; h_a = (h_b@W1)*di_is ; h_b = relu(LN(h_a))*do_is
    k_agg128<<<NB_WAVE, 256, 0, stream>>>(h_a, row_ptr, col, (const float*)nullptr, h_b);
    k_gemm2<<<NB_M64, 256, 0, stream>>>(h_b, W1, di_is, h_a);
    k_ln128<<<NB_WAVE, 256, 0, stream>>>(h_a, g1, b1, do_is, h_b);

    // Layer 2: h_c = h_b@W2 ; out = agg(h_c)*di_is + b2
    k_gemm3<<<NB_M64, 256, 0, stream>>>(h_b, W2, h_c);
    k_agg40<<<NB_WAVE, 256, 0, stream>>>(h_c, row_ptr, col, di_is, b2, out);
}

// Round 2
// 586.226 us; speedup vs baseline: 1.2533x; 1.2533x over previous
//
#include <hip/hip_runtime.h>
#include <math.h>

#define N_NODES 50000
#define N_EDGES 800000
#define IN_F 768
#define HID 128
#define CLS 40
#define EPS 1e-5f

typedef __attribute__((ext_vector_type(8))) short short8;
typedef __attribute__((ext_vector_type(4))) float f32x4;

__device__ inline unsigned short f2bf(float f) {
    union { float f; unsigned u; } x;
    x.f = f;
    unsigned u = x.u;
    return (unsigned short)((u + 0x7FFF + ((u >> 16) & 1)) >> 16);
}

// ---------------- degree / normalization ----------------

__global__ void k_deg(const int* __restrict__ src, const int* __restrict__ dst,
                      int* __restrict__ deg_out, int* __restrict__ deg_in) {
    int e = blockIdx.x * 256 + threadIdx.x;
    if (e < N_EDGES) {
        atomicAdd(&deg_out[src[e]], 1);
        atomicAdd(&deg_in[dst[e]], 1);
    }
}

__global__ void k_rsqrt(const int* __restrict__ deg_out, const int* __restrict__ deg_in,
                        float* __restrict__ do_is, float* __restrict__ di_is) {
    int i = blockIdx.x * 256 + threadIdx.x;
    if (i < N_NODES) {
        do_is[i] = rsqrtf((float)max(deg_out[i], 1));
        di_is[i] = rsqrtf((float)max(deg_in[i], 1));
    }
}

// ---------------- CSR build: scan + fill ----------------

__global__ void k_scanA(const int* __restrict__ deg_in, int* __restrict__ tmp,
                        int* __restrict__ bsum) {
    __shared__ int s[256];
    int t = threadIdx.x;
    int i = blockIdx.x * 256 + t;
    int v = (i < N_NODES) ? deg_in[i] : 0;
    s[t] = v;
    __syncthreads();
    for (int off = 1; off < 256; off <<= 1) {
        int x = 0;
        if (t >= off) x = s[t - off];
        __syncthreads();
        if (t >= off) s[t] += x;
        __syncthreads();
    }
    if (i < N_NODES) tmp[i] = s[t];
    if (t == 255) bsum[blockIdx.x] = s[255];
}

__global__ void k_scanB(const int* __restrict__ bsum, int* __restrict__ boff, int nb) {
    if (threadIdx.x == 0 && blockIdx.x == 0) {
        int run = 0;
        for (int b = 0; b < nb; b++) { boff[b] = run; run += bsum[b]; }
    }
}

__global__ void k_scanC(const int* __restrict__ tmp, const int* __restrict__ deg_in,
                        const int* __restrict__ boff, int* __restrict__ row_ptr) {
    int i = blockIdx.x * 256 + threadIdx.x;
    if (i < N_NODES) row_ptr[i] = tmp[i] - deg_in[i] + boff[blockIdx.x];
    if (i == 0) row_ptr[N_NODES] = N_EDGES;
}

__global__ void k_fill(const int* __restrict__ src, const int* __restrict__ dst,
                       const int* __restrict__ row_ptr, int* __restrict__ cnt,
                       int* __restrict__ col) {
    int e = blockIdx.x * 256 + threadIdx.x;
    if (e < N_EDGES) {
        int d = dst[e];
        int pos = row_ptr[d] + atomicAdd(&cnt[d], 1);
        col[pos] = src[e];
    }
}

// ---------------- fused LN(768) + bf16 convert (wave per row) ----------------

__global__ void k_lncvt(const float* __restrict__ feat, const float* __restrict__ g,
                        const float* __restrict__ b, unsigned short* __restrict__ Abf) {
    int wid = (blockIdx.x * 256 + threadIdx.x) >> 6;
    int lane = threadIdx.x & 63;
    if (wid >= N_NODES) return;
    const float4* x4 = (const float4*)(feat + (size_t)wid * IN_F);
    float4 v[3];
    float s = 0.f, q = 0.f;
#pragma unroll
    for (int i = 0; i < 3; i++) {
        float4 t = x4[lane + 64 * i];
        v[i] = t;
        s += t.x + t.y + t.z + t.w;
        q += t.x * t.x + t.y * t.y + t.z * t.z + t.w * t.w;
    }
#pragma unroll
    for (int m = 1; m < 64; m <<= 1) {
        s += __shfl_xor(s, m);
        q += __shfl_xor(q, m);
    }
    float mu = s * (1.f / (float)IN_F);
    float var = q * (1.f / (float)IN_F) - mu * mu;
    float rstd = rsqrtf(var + EPS);
    ushort4* orow = (ushort4*)(Abf + (size_t)wid * IN_F);
    const float4* g4 = (const float4*)g;
    const float4* b4 = (const float4*)b;
#pragma unroll
    for (int i = 0; i < 3; i++) {
        int f = lane + 64 * i;
        float4 gg = g4[f];
        float4 bb = b4[f];
        ushort4 o;
        o.x = f2bf((v[i].x - mu) * rstd * gg.x + bb.x);
        o.y = f2bf((v[i].y - mu) * rstd * gg.y + bb.y);
        o.z = f2bf((v[i].z - mu) * rstd * gg.z + bb.z);
        o.w = f2bf((v[i].w - mu) * rstd * gg.w + bb.w);
        orow[f] = o;
    }
}

// ---------------- W0 transpose + convert: [768][128] f32 -> [128][768] bf16 ----------------

__global__ void k_cvtW(const float* __restrict__ W0, unsigned short* __restrict__ Wt) {
    int idx = blockIdx.x * 256 + threadIdx.x;
    if (idx < IN_F * HID) {
        int k = idx >> 7, c = idx & 127;
        Wt[(size_t)c * IN_F + k] = f2bf(W0[idx]);
    }
}

// ---------------- GEMM1 (MFMA): out = (Abf @ Wt^T) * do_is[row]  [M,768]x[768,128] ----------------
// block = 256 (4 waves); block tile 64 rows x 128 cols; wave = 64 rows x 32 cols.
// A frag: row = base + (l&15), k = k0 + 8*(l>>4) + 0..7 (short8 contiguous)
// B frag: col = base + (l&15), same k run from Wt[col][k]
// C/D: col = c0 + n*16 + (l&15), row = r0 + m*16 + (l>>4)*4 + j  [verified m89 mapping]

__global__ void k_gemm1_mfma(const unsigned short* __restrict__ Abf,
                             const unsigned short* __restrict__ Wt,
                             const float* __restrict__ do_is,
                             float* __restrict__ out) {
    int t = threadIdx.x;
    int w = t >> 6, l = t & 63;
    int r0 = blockIdx.x * 64;
    int c0 = w * 32;
    int lrow = l & 15;
    int lk8 = (l >> 4);  // k-offset in short8 units

    const short8* ap[4];
#pragma unroll
    for (int m = 0; m < 4; m++) {
        int row = r0 + m * 16 + lrow;
        if (row > N_NODES - 1) row = N_NODES - 1;
        ap[m] = (const short8*)(Abf + (size_t)row * IN_F) + lk8;
    }
    const short8* bp[2];
#pragma unroll
    for (int n = 0; n < 2; n++) {
        int colr = c0 + n * 16 + lrow;
        bp[n] = (const short8*)(Wt + (size_t)colr * IN_F) + lk8;
    }

    f32x4 acc[4][2] = {};
#pragma unroll
    for (int k0 = 0; k0 < IN_F / 8; k0 += 4) {  // 24 iterations, 32 k per iter
        short8 bv[2];
        bv[0] = bp[0][k0];
        bv[1] = bp[1][k0];
#pragma unroll
        for (int m = 0; m < 4; m++) {
            short8 av = ap[m][k0];
            acc[m][0] = __builtin_amdgcn_mfma_f32_16x16x32_bf16(av, bv[0], acc[m][0], 0, 0, 0);
            acc[m][1] = __builtin_amdgcn_mfma_f32_16x16x32_bf16(av, bv[1], acc[m][1], 0, 0, 0);
        }
    }

#pragma unroll
    for (int m = 0; m < 4; m++) {
#pragma unroll
        for (int j = 0; j < 4; j++) {
            int row = r0 + m * 16 + (l >> 4) * 4 + j;
            if (row < N_NODES) {
                float s = do_is[row];
                out[(size_t)row * HID + c0 + (l & 15)] = acc[m][0][j] * s;
                out[(size_t)row * HID + c0 + 16 + (l & 15)] = acc[m][1][j] * s;
            }
        }
    }
}

// ---------------- GEMM2: out = (A@W1) * di_is[row]  [M,128]x[128,128] ----------------

__global__ void k_gemm2(const float* __restrict__ A, const float* __restrict__ W,
                        const float* __restrict__ di_is, float* __restrict__ out) {
    __shared__ float As[16][64];
    __shared__ float Bs[16][128];
    int t = threadIdx.x;
    int row0 = blockIdx.x * 64;
    int r8 = (t >> 5) * 8;
    int c4 = (t & 31) * 4;
    float acc[8][4] = {};
    for (int k0 = 0; k0 < HID; k0 += 16) {
        for (int i = 0; i < 4; i++) {
            int idx = t + i * 256;
            int kk = idx & 15, m = idx >> 4;
            int row = row0 + m;
            As[kk][m] = (row < N_NODES) ? A[(size_t)row * HID + k0 + kk] : 0.f;
        }
        for (int i = 0; i < 8; i++) {
            int idx = t + i * 256;
            int c = idx & 127, kk = idx >> 7;
            Bs[kk][c] = W[(size_t)(k0 + kk) * HID + c];
        }
        __syncthreads();
        for (int kk = 0; kk < 16; kk++) {
            float bb[4];
            for (int c = 0; c < 4; c++) bb[c] = Bs[kk][c4 + c];
            for (int r = 0; r < 8; r++) {
                float a = As[kk][r8 + r];
                for (int c = 0; c < 4; c++) acc[r][c] = fmaf(a, bb[c], acc[r][c]);
            }
        }
        __syncthreads();
    }
    for (int r = 0; r < 8; r++) {
        int row = row0 + r8 + r;
        if (row < N_NODES) {
            float s = di_is[row];
            for (int c = 0; c < 4; c++) out[(size_t)row * HID + c4 + c] = acc[r][c] * s;
        }
    }
}

// ---------------- GEMM3: out = A@W2  [M,128]x[128,40] ----------------

__global__ void k_gemm3(const float* __restrict__ A, const float* __restrict__ W,
                        float* __restrict__ out) {
    __shared__ float As[16][64];
    __shared__ float Bs[16][40];
    int t = threadIdx.x;
    int row0 = blockIdx.x * 64;
    int r = t >> 2;
    int c0 = (t & 3) * 10;
    float acc[10] = {};
    for (int k0 = 0; k0 < HID; k0 += 16) {
        for (int i = 0; i < 4; i++) {
            int idx = t + i * 256;
            int kk = idx & 15, m = idx >> 4;
            int row = row0 + m;
            As[kk][m] = (row < N_NODES) ? A[(size_t)row * HID + k0 + kk] : 0.f;
        }
        for (int i = 0; i < 3; i++) {
            int idx = t + i * 256;
            if (idx < 16 * CLS) {
                int c = idx % CLS, kk = idx / CLS;
                Bs[kk][c] = W[(size_t)(k0 + kk) * CLS + c];
            }
        }
        __syncthreads();
        for (int kk = 0; kk < 16; kk++) {
            float a = As[kk][r];
            for (int c = 0; c < 10; c++) acc[c] = fmaf(a, Bs[kk][c0 + c], acc[c]);
        }
        __syncthreads();
    }
    int row = row0 + r;
    if (row < N_NODES) {
        for (int c = 0; c < 10; c++) out[(size_t)row * CLS + c0 + c] = acc[c];
    }
}

// ---------------- CSR aggregation, 128 features (wave per node) ----------------

__global__ void k_agg128(const float* __restrict__ h, const int* __restrict__ row_ptr,
                         const int* __restrict__ col, const float* __restrict__ scale,
                         float* __restrict__ out) {
    int wid = (blockIdx.x * blockDim.x + threadIdx.x) >> 6;
    int lane = threadIdx.x & 63;
    if (wid >= N_NODES) return;
    int s = row_ptr[wid], e = row_ptr[wid + 1];
    const float2* h2 = (const float2*)h;
    float2 acc = make_float2(0.f, 0.f);
    for (int i = s; i < e; i++) {
        int sn = col[i];
        float2 v = h2[(size_t)sn * 64 + lane];
        acc.x += v.x;
        acc.y += v.y;
    }
    float sc = scale ? scale[wid] : 1.f;
    ((float2*)out)[(size_t)wid * 64 + lane] = make_float2(acc.x * sc, acc.y * sc);
}

// ---------------- CSR aggregation, 40 features + bias (wave per node) ----------------

__global__ void k_agg40(const float* __restrict__ h, const int* __restrict__ row_ptr,
                        const int* __restrict__ col, const float* __restrict__ di_is,
                        const float* __restrict__ b2, float* __restrict__ out) {
    int wid = (blockIdx.x * blockDim.x + threadIdx.x) >> 6;
    int lane = threadIdx.x & 63;
    if (wid >= N_NODES) return;
    if (lane < CLS) {
        int s = row_ptr[wid], e = row_ptr[wid + 1];
        float acc = 0.f;
        for (int i = s; i < e; i++) acc += h[(size_t)col[i] * CLS + lane];
        out[(size_t)wid * CLS + lane] = acc * di_is[wid] + b2[lane];
    }
}

// ---------------- LN(128) + ReLU + x do_is (wave per row) ----------------

__global__ void k_ln128(const float* __restrict__ in, const float* __restrict__ g,
                        const float* __restrict__ b, const float* __restrict__ do_is,
                        float* __restrict__ out) {
    int wid = (blockIdx.x * blockDim.x + threadIdx.x) >> 6;
    int lane = threadIdx.x & 63;
    if (wid >= N_NODES) return;
    const float2* in2 = (const float2*)in;
    float2 v = in2[(size_t)wid * 64 + lane];
    float s = v.x + v.y;
    float q = v.x * v.x + v.y * v.y;
    for (int m = 1; m < 64; m <<= 1) {
        s += __shfl_xor(s, m);
        q += __shfl_xor(q, m);
    }
    float mu = s * (1.f / 128.f);
    float var = q * (1.f / 128.f) - mu * mu;
    float rstd = rsqrtf(var + EPS);
    float2 gg = ((const float2*)g)[lane];
    float2 bb = ((const float2*)b)[lane];
    float sc = do_is[wid];
    float y0 = fmaxf((v.x - mu) * rstd * gg.x + bb.x, 0.f) * sc;
    float y1 = fmaxf((v.y - mu) * rstd * gg.y + bb.y, 0.f) * sc;
    ((float2*)out)[(size_t)wid * 64 + lane] = make_float2(y0, y1);
}

// ---------------- launch ----------------

extern "C" void kernel_launch(void* const* d_in, const int* in_sizes, int n_in,
                              void* d_out, int out_size, void* d_ws, size_t ws_size,
                              hipStream_t stream) {
    (void)in_sizes; (void)n_in; (void)out_size; (void)ws_size;
    const float* feat = (const float*)d_in[0];
    const int*   src  = (const int*)d_in[1];
    const int*   dst  = (const int*)d_in[2];
    const float* W0   = (const float*)d_in[3];
    const float* W1   = (const float*)d_in[4];
    const float* W2   = (const float*)d_in[5];
    const float* b2   = (const float*)d_in[6];
    const float* g_in = (const float*)d_in[7];
    const float* b_in = (const float*)d_in[8];
    const float* g0   = (const float*)d_in[9];
    const float* b0   = (const float*)d_in[10];
    const float* g1   = (const float*)d_in[11];
    const float* b1   = (const float*)d_in[12];
    float* out = (float*)d_out;

    char* w = (char*)d_ws;
    size_t off = 0;
    auto take = [&](size_t bytes) -> void* {
        void* p = w + off;
        off += (bytes + 255) & ~(size_t)255;
        return p;
    };
    int*   deg_out_i = (int*)take((size_t)N_NODES * 4);
    int*   deg_in_i  = (int*)take((size_t)N_NODES * 4);
    float* do_is     = (float*)take((size_t)N_NODES * 4);
    float* di_is     = (float*)take((size_t)N_NODES * 4);
    int*   tmp       = (int*)take((size_t)N_NODES * 4);
    int*   bsum      = (int*)take(256 * 4);
    int*   boff      = (int*)take(256 * 4);
    int*   row_ptr   = (int*)take((size_t)(N_NODES + 1) * 4);
    int*   cnt       = (int*)take((size_t)N_NODES * 4);
    int*   col       = (int*)take((size_t)N_EDGES * 4);
    unsigned short* Abf = (unsigned short*)take((size_t)N_NODES * IN_F * 2);
    unsigned short* Wt  = (unsigned short*)take((size_t)IN_F * HID * 2);
    float* h_a       = (float*)take((size_t)N_NODES * HID * 4);
    float* h_b       = (float*)take((size_t)N_NODES * HID * 4);
    float* h_c       = (float*)take((size_t)N_NODES * CLS * 4);

    const int NB_E = (N_EDGES + 255) / 256;         // 3125
    const int NB_N = (N_NODES + 255) / 256;         // 196
    const int NB_M64 = (N_NODES + 63) / 64;         // 782
    const int NB_WAVE = (N_NODES * 64 + 255) / 256; // 12500

    hipMemsetAsync(deg_out_i, 0, (size_t)N_NODES * 4, stream);
    hipMemsetAsync(deg_in_i, 0, (size_t)N_NODES * 4, stream);
    hipMemsetAsync(cnt, 0, (size_t)N_NODES * 4, stream);

    k_deg<<<NB_E, 256, 0, stream>>>(src, dst, deg_out_i, deg_in_i);
    k_rsqrt<<<NB_N, 256, 0, stream>>>(deg_out_i, deg_in_i, do_is, di_is);

    k_scanA<<<NB_N, 256, 0, stream>>>(deg_in_i, tmp, bsum);
    k_scanB<<<1, 1, 0, stream>>>(bsum, boff, NB_N);
    k_scanC<<<NB_N, 256, 0, stream>>>(tmp, deg_in_i, boff, row_ptr);
    k_fill<<<NB_E, 256, 0, stream>>>(src, dst, row_ptr, cnt, col);

    // LN(768) + bf16 convert; W0 -> bf16 transposed
    k_lncvt<<<NB_WAVE, 256, 0, stream>>>(feat, g_in, b_in, Abf);
    k_cvtW<<<(IN_F * HID + 255) / 256, 256, 0, stream>>>(W0, Wt);

    // Layer 0: h_a = (LN(feat)@W0)*do_is ; h_b = agg(h_a)*di_is ; h_a = relu(LN(h_b))*do_is
    k_gemm1_mfma<<<NB_M64, 256, 0, stream>>>(Abf, Wt, do_is, h_a);
    k_agg128<<<NB_WAVE, 256, 0, stream>>>(h_a, row_ptr, col, di_is, h_b);
    k_ln128<<<NB_WAVE, 256, 0, stream>>>(h_b, g0, b0, do_is, h_a);

    // Layer 1: h_b = agg(h_a) ; h_a = (h_b@W1)*di_is ; h_b = relu(LN(h_a))*do_is
    k_agg128<<<NB_WAVE, 256, 0, stream>>>(h_a, row_ptr, col, (const float*)nullptr, h_b);
    k_gemm2<<<NB_M64, 256, 0, stream>>>(h_b, W1, di_is, h_a);
    k_ln128<<<NB_WAVE, 256, 0, stream>>>(h_a, g1, b1, do_is, h_b);

    // Layer 2: h_c = h_b@W2 ; out = agg(h_c)*di_is + b2
    k_gemm3<<<NB_M64, 256, 0, stream>>>(h_b, W2, h_c);
    k_agg40<<<NB_WAVE, 256, 0, stream>>>(h_c, row_ptr, col, di_is, b2, out);
}

// Round 3
// 506.927 us; speedup vs baseline: 1.4494x; 1.1564x over previous
//
#include <hip/hip_runtime.h>
#include <math.h>

#define N_NODES 50000
#define N_EDGES 800000
#define IN_F 768
#define HID 128
#define CLS 40
#define CLSP 48
#define EPS 1e-5f

typedef __attribute__((ext_vector_type(8))) short short8;
typedef __attribute__((ext_vector_type(4))) float f32x4;

__device__ inline unsigned short f2bf(float f) {
    union { float f; unsigned u; } x;
    x.f = f;
    unsigned u = x.u;
    return (unsigned short)((u + 0x7FFF + ((u >> 16) & 1)) >> 16);
}

__device__ inline float bf2f(unsigned short u) {
    union { unsigned u; float f; } x;
    x.u = ((unsigned)u) << 16;
    return x.f;
}

__device__ inline unsigned pack2bf(float a, float b) {
    return (unsigned)f2bf(a) | ((unsigned)f2bf(b) << 16);
}

// ---------------- degree / normalization ----------------

__global__ void k_deg(const int* __restrict__ src, const int* __restrict__ dst,
                      int* __restrict__ deg_out, int* __restrict__ deg_in) {
    int e = blockIdx.x * 256 + threadIdx.x;
    if (e < N_EDGES) {
        atomicAdd(&deg_out[src[e]], 1);
        atomicAdd(&deg_in[dst[e]], 1);
    }
}

__global__ void k_rsqrt(const int* __restrict__ deg_out, const int* __restrict__ deg_in,
                        float* __restrict__ do_is, float* __restrict__ di_is) {
    int i = blockIdx.x * 256 + threadIdx.x;
    if (i < N_NODES) {
        do_is[i] = rsqrtf((float)max(deg_out[i], 1));
        di_is[i] = rsqrtf((float)max(deg_in[i], 1));
    }
}

// ---------------- CSR build: scan + fill ----------------

__global__ void k_scanA(const int* __restrict__ deg_in, int* __restrict__ tmp,
                        int* __restrict__ bsum) {
    __shared__ int s[256];
    int t = threadIdx.x;
    int i = blockIdx.x * 256 + t;
    int v = (i < N_NODES) ? deg_in[i] : 0;
    s[t] = v;
    __syncthreads();
    for (int off = 1; off < 256; off <<= 1) {
        int x = 0;
        if (t >= off) x = s[t - off];
        __syncthreads();
        if (t >= off) s[t] += x;
        __syncthreads();
    }
    if (i < N_NODES) tmp[i] = s[t];
    if (t == 255) bsum[blockIdx.x] = s[255];
}

__global__ void k_scanB(const int* __restrict__ bsum, int* __restrict__ boff, int nb) {
    if (threadIdx.x == 0 && blockIdx.x == 0) {
        int run = 0;
        for (int b = 0; b < nb; b++) { boff[b] = run; run += bsum[b]; }
    }
}

__global__ void k_scanC(const int* __restrict__ tmp, const int* __restrict__ deg_in,
                        const int* __restrict__ boff, int* __restrict__ row_ptr) {
    int i = blockIdx.x * 256 + threadIdx.x;
    if (i < N_NODES) row_ptr[i] = tmp[i] - deg_in[i] + boff[blockIdx.x];
    if (i == 0) row_ptr[N_NODES] = N_EDGES;
}

__global__ void k_fill(const int* __restrict__ src, const int* __restrict__ dst,
                       const int* __restrict__ row_ptr, int* __restrict__ cnt,
                       int* __restrict__ col) {
    int e = blockIdx.x * 256 + threadIdx.x;
    if (e < N_EDGES) {
        int d = dst[e];
        int pos = row_ptr[d] + atomicAdd(&cnt[d], 1);
        col[pos] = src[e];
    }
}

// ---------------- fused LN(768) + bf16 convert (wave per row) ----------------

__global__ void k_lncvt(const float* __restrict__ feat, const float* __restrict__ g,
                        const float* __restrict__ b, unsigned short* __restrict__ Abf) {
    int wid = (blockIdx.x * 256 + threadIdx.x) >> 6;
    int lane = threadIdx.x & 63;
    if (wid >= N_NODES) return;
    const float4* x4 = (const float4*)(feat + (size_t)wid * IN_F);
    float4 v[3];
    float s = 0.f, q = 0.f;
#pragma unroll
    for (int i = 0; i < 3; i++) {
        float4 t = x4[lane + 64 * i];
        v[i] = t;
        s += t.x + t.y + t.z + t.w;
        q += t.x * t.x + t.y * t.y + t.z * t.z + t.w * t.w;
    }
#pragma unroll
    for (int m = 1; m < 64; m <<= 1) {
        s += __shfl_xor(s, m);
        q += __shfl_xor(q, m);
    }
    float mu = s * (1.f / (float)IN_F);
    float var = q * (1.f / (float)IN_F) - mu * mu;
    float rstd = rsqrtf(var + EPS);
    ushort4* orow = (ushort4*)(Abf + (size_t)wid * IN_F);
    const float4* g4 = (const float4*)g;
    const float4* b4 = (const float4*)b;
#pragma unroll
    for (int i = 0; i < 3; i++) {
        int f = lane + 64 * i;
        float4 gg = g4[f];
        float4 bb = b4[f];
        ushort4 o;
        o.x = f2bf((v[i].x - mu) * rstd * gg.x + bb.x);
        o.y = f2bf((v[i].y - mu) * rstd * gg.y + bb.y);
        o.z = f2bf((v[i].z - mu) * rstd * gg.z + bb.z);
        o.w = f2bf((v[i].w - mu) * rstd * gg.w + bb.w);
        orow[f] = o;
    }
}

// ---------------- W transpose+convert: [K][C] f32 -> [Cp][K] bf16 (pad cols with 0) ----------------

__global__ void k_cvtWT(const float* __restrict__ W, unsigned short* __restrict__ Wt,
                        int K, int C, int Cp) {
    int idx = blockIdx.x * 256 + threadIdx.x;
    if (idx < K * Cp) {
        int c = idx / K, k = idx % K;
        Wt[idx] = (c < C) ? f2bf(W[(size_t)k * C + c]) : (unsigned short)0;
    }
}

// ---------------- GEMM1 (MFMA): h0 = bf16( (Abf @ Wt0^T) * do_is[row] )  [M,768]x[768,128] ----------------

__global__ void k_gemm1_mfma(const unsigned short* __restrict__ Abf,
                             const unsigned short* __restrict__ Wt,
                             const float* __restrict__ do_is,
                             unsigned short* __restrict__ out) {
    int t = threadIdx.x;
    int w = t >> 6, l = t & 63;
    int r0 = blockIdx.x * 64;
    int c0 = w * 32;
    int lrow = l & 15;
    int lk8 = (l >> 4);

    const short8* ap[4];
#pragma unroll
    for (int m = 0; m < 4; m++) {
        int row = r0 + m * 16 + lrow;
        if (row > N_NODES - 1) row = N_NODES - 1;
        ap[m] = (const short8*)(Abf + (size_t)row * IN_F) + lk8;
    }
    const short8* bp[2];
#pragma unroll
    for (int n = 0; n < 2; n++) {
        int colr = c0 + n * 16 + lrow;
        bp[n] = (const short8*)(Wt + (size_t)colr * IN_F) + lk8;
    }

    f32x4 acc[4][2] = {};
#pragma unroll
    for (int k0 = 0; k0 < IN_F / 8; k0 += 4) {
        short8 bv[2];
        bv[0] = bp[0][k0];
        bv[1] = bp[1][k0];
#pragma unroll
        for (int m = 0; m < 4; m++) {
            short8 av = ap[m][k0];
            acc[m][0] = __builtin_amdgcn_mfma_f32_16x16x32_bf16(av, bv[0], acc[m][0], 0, 0, 0);
            acc[m][1] = __builtin_amdgcn_mfma_f32_16x16x32_bf16(av, bv[1], acc[m][1], 0, 0, 0);
        }
    }

#pragma unroll
    for (int m = 0; m < 4; m++) {
#pragma unroll
        for (int j = 0; j < 4; j++) {
            int row = r0 + m * 16 + (l >> 4) * 4 + j;
            if (row < N_NODES) {
                float s = do_is[row];
                out[(size_t)row * HID + c0 + (l & 15)] = f2bf(acc[m][0][j] * s);
                out[(size_t)row * HID + c0 + 16 + (l & 15)] = f2bf(acc[m][1][j] * s);
            }
        }
    }
}

// ---------------- GEMM2 (MFMA): ha = (hb @ Wt1^T) * di_is[row]  [M,128]x[128,128] f32 out ----------------

__global__ void k_gemm2_mfma(const unsigned short* __restrict__ A,
                             const unsigned short* __restrict__ Wt,
                             const float* __restrict__ di_is,
                             float* __restrict__ out) {
    int t = threadIdx.x;
    int w = t >> 6, l = t & 63;
    int r0 = blockIdx.x * 64;
    int c0 = w * 32;
    int lrow = l & 15;
    int lk8 = (l >> 4);

    const short8* ap[4];
#pragma unroll
    for (int m = 0; m < 4; m++) {
        int row = r0 + m * 16 + lrow;
        if (row > N_NODES - 1) row = N_NODES - 1;
        ap[m] = (const short8*)(A + (size_t)row * HID) + lk8;
    }
    const short8* bp[2];
#pragma unroll
    for (int n = 0; n < 2; n++) {
        int colr = c0 + n * 16 + lrow;
        bp[n] = (const short8*)(Wt + (size_t)colr * HID) + lk8;
    }

    f32x4 acc[4][2] = {};
#pragma unroll
    for (int k0 = 0; k0 < HID / 8; k0 += 4) {
        short8 bv[2];
        bv[0] = bp[0][k0];
        bv[1] = bp[1][k0];
#pragma unroll
        for (int m = 0; m < 4; m++) {
            short8 av = ap[m][k0];
            acc[m][0] = __builtin_amdgcn_mfma_f32_16x16x32_bf16(av, bv[0], acc[m][0], 0, 0, 0);
            acc[m][1] = __builtin_amdgcn_mfma_f32_16x16x32_bf16(av, bv[1], acc[m][1], 0, 0, 0);
        }
    }

#pragma unroll
    for (int m = 0; m < 4; m++) {
#pragma unroll
        for (int j = 0; j < 4; j++) {
            int row = r0 + m * 16 + (l >> 4) * 4 + j;
            if (row < N_NODES) {
                float s = di_is[row];
                out[(size_t)row * HID + c0 + (l & 15)] = acc[m][0][j] * s;
                out[(size_t)row * HID + c0 + 16 + (l & 15)] = acc[m][1][j] * s;
            }
        }
    }
}

// ---------------- GEMM3 (MFMA): hc = bf16(h2 @ Wt2^T)  [M,128]x[128,40->48] ----------------
// 4 waves: each wave 16 rows x 48 cols

__global__ void k_gemm3_mfma(const unsigned short* __restrict__ A,
                             const unsigned short* __restrict__ Wt,
                             unsigned short* __restrict__ out) {
    int t = threadIdx.x;
    int w = t >> 6, l = t & 63;
    int r0 = blockIdx.x * 64 + w * 16;
    int lrow = l & 15;
    int lk8 = (l >> 4);

    int arow = r0 + lrow;
    if (arow > N_NODES - 1) arow = N_NODES - 1;
    const short8* ap = (const short8*)(A + (size_t)arow * HID) + lk8;
    const short8* bp[3];
#pragma unroll
    for (int n = 0; n < 3; n++) {
        int colr = n * 16 + lrow;
        bp[n] = (const short8*)(Wt + (size_t)colr * HID) + lk8;
    }

    f32x4 acc[3] = {};
#pragma unroll
    for (int k0 = 0; k0 < HID / 8; k0 += 4) {
        short8 av = ap[k0];
#pragma unroll
        for (int n = 0; n < 3; n++) {
            acc[n] = __builtin_amdgcn_mfma_f32_16x16x32_bf16(av, bp[n][k0], acc[n], 0, 0, 0);
        }
    }

#pragma unroll
    for (int n = 0; n < 3; n++) {
        int col = n * 16 + (l & 15);
        if (col < CLS) {
#pragma unroll
            for (int j = 0; j < 4; j++) {
                int row = r0 + (l >> 4) * 4 + j;
                if (row < N_NODES) out[(size_t)row * CLS + col] = f2bf(acc[n][j]);
            }
        }
    }
}

// ---------------- fused agg + LN + ReLU (layer 0), bf16 in/out, wave per node ----------------
// h1 = bf16( relu( LN( agg(h0)*di_is ) ) * do_is )

__global__ void k_aggln(const unsigned short* __restrict__ h, const int* __restrict__ row_ptr,
                        const int* __restrict__ col, const float* __restrict__ di_is,
                        const float* __restrict__ do_is, const float* __restrict__ g,
                        const float* __restrict__ b, unsigned* __restrict__ out) {
    int wid = (blockIdx.x * blockDim.x + threadIdx.x) >> 6;
    int lane = threadIdx.x & 63;
    if (wid >= N_NODES) return;
    int s0 = row_ptr[wid], e0 = row_ptr[wid + 1];
    const unsigned* h2 = (const unsigned*)h;
    float ax = 0.f, ay = 0.f;
    for (int i = s0; i < e0; i++) {
        unsigned u = h2[(size_t)col[i] * 64 + lane];
        ax += bf2f((unsigned short)(u & 0xFFFF));
        ay += bf2f((unsigned short)(u >> 16));
    }
    float di = di_is[wid];
    ax *= di; ay *= di;
    float s = ax + ay;
    float q = ax * ax + ay * ay;
#pragma unroll
    for (int m = 1; m < 64; m <<= 1) {
        s += __shfl_xor(s, m);
        q += __shfl_xor(q, m);
    }
    float mu = s * (1.f / 128.f);
    float var = q * (1.f / 128.f) - mu * mu;
    float rstd = rsqrtf(var + EPS);
    float2 gg = ((const float2*)g)[lane];
    float2 bb = ((const float2*)b)[lane];
    float sc = do_is[wid];
    float y0 = fmaxf((ax - mu) * rstd * gg.x + bb.x, 0.f) * sc;
    float y1 = fmaxf((ay - mu) * rstd * gg.y + bb.y, 0.f) * sc;
    out[(size_t)wid * 64 + lane] = pack2bf(y0, y1);
}

// ---------------- agg (layer 1), bf16 in, bf16 raw-sum out, wave per node ----------------

__global__ void k_agg128b(const unsigned short* __restrict__ h, const int* __restrict__ row_ptr,
                          const int* __restrict__ col, unsigned* __restrict__ out) {
    int wid = (blockIdx.x * blockDim.x + threadIdx.x) >> 6;
    int lane = threadIdx.x & 63;
    if (wid >= N_NODES) return;
    int s0 = row_ptr[wid], e0 = row_ptr[wid + 1];
    const unsigned* h2 = (const unsigned*)h;
    float ax = 0.f, ay = 0.f;
    for (int i = s0; i < e0; i++) {
        unsigned u = h2[(size_t)col[i] * 64 + lane];
        ax += bf2f((unsigned short)(u & 0xFFFF));
        ay += bf2f((unsigned short)(u >> 16));
    }
    out[(size_t)wid * 64 + lane] = pack2bf(ax, ay);
}

// ---------------- LN(128) + ReLU + x do_is : f32 in -> bf16 out (wave per row) ----------------

__global__ void k_ln128f(const float* __restrict__ in, const float* __restrict__ g,
                         const float* __restrict__ b, const float* __restrict__ do_is,
                         unsigned* __restrict__ out) {
    int wid = (blockIdx.x * blockDim.x + threadIdx.x) >> 6;
    int lane = threadIdx.x & 63;
    if (wid >= N_NODES) return;
    float2 v = ((const float2*)in)[(size_t)wid * 64 + lane];
    float s = v.x + v.y;
    float q = v.x * v.x + v.y * v.y;
#pragma unroll
    for (int m = 1; m < 64; m <<= 1) {
        s += __shfl_xor(s, m);
        q += __shfl_xor(q, m);
    }
    float mu = s * (1.f / 128.f);
    float var = q * (1.f / 128.f) - mu * mu;
    float rstd = rsqrtf(var + EPS);
    float2 gg = ((const float2*)g)[lane];
    float2 bb = ((const float2*)b)[lane];
    float sc = do_is[wid];
    float y0 = fmaxf((v.x - mu) * rstd * gg.x + bb.x, 0.f) * sc;
    float y1 = fmaxf((v.y - mu) * rstd * gg.y + bb.y, 0.f) * sc;
    out[(size_t)wid * 64 + lane] = pack2bf(y0, y1);
}

// ---------------- agg (layer 2), 40 feats bf16 in + bias, f32 out, wave per node ----------------

__global__ void k_agg40b(const unsigned short* __restrict__ h, const int* __restrict__ row_ptr,
                         const int* __restrict__ col, const float* __restrict__ di_is,
                         const float* __restrict__ b2, float* __restrict__ out) {
    int wid = (blockIdx.x * blockDim.x + threadIdx.x) >> 6;
    int lane = threadIdx.x & 63;
    if (wid >= N_NODES) return;
    if (lane < CLS) {
        int s0 = row_ptr[wid], e0 = row_ptr[wid + 1];
        float acc = 0.f;
        for (int i = s0; i < e0; i++) acc += bf2f(h[(size_t)col[i] * CLS + lane]);
        out[(size_t)wid * CLS + lane] = acc * di_is[wid] + b2[lane];
    }
}

// ---------------- launch ----------------

extern "C" void kernel_launch(void* const* d_in, const int* in_sizes, int n_in,
                              void* d_out, int out_size, void* d_ws, size_t ws_size,
                              hipStream_t stream) {
    (void)in_sizes; (void)n_in; (void)out_size; (void)ws_size;
    const float* feat = (const float*)d_in[0];
    const int*   src  = (const int*)d_in[1];
    const int*   dst  = (const int*)d_in[2];
    const float* W0   = (const float*)d_in[3];
    const float* W1   = (const float*)d_in[4];
    const float* W2   = (const float*)d_in[5];
    const float* b2   = (const float*)d_in[6];
    const float* g_in = (const float*)d_in[7];
    const float* b_in = (const float*)d_in[8];
    const float* g0   = (const float*)d_in[9];
    const float* b0   = (const float*)d_in[10];
    const float* g1   = (const float*)d_in[11];
    const float* b1   = (const float*)d_in[12];
    float* out = (float*)d_out;

    char* w = (char*)d_ws;
    size_t off = 0;
    auto take = [&](size_t bytes) -> void* {
        void* p = w + off;
        off += (bytes + 255) & ~(size_t)255;
        return p;
    };
    int*   deg_out_i = (int*)take((size_t)N_NODES * 4);
    int*   deg_in_i  = (int*)take((size_t)N_NODES * 4);
    float* do_is     = (float*)take((size_t)N_NODES * 4);
    float* di_is     = (float*)take((size_t)N_NODES * 4);
    int*   tmp       = (int*)take((size_t)N_NODES * 4);
    int*   bsum      = (int*)take(256 * 4);
    int*   boff      = (int*)take(256 * 4);
    int*   row_ptr   = (int*)take((size_t)(N_NODES + 1) * 4);
    int*   cnt       = (int*)take((size_t)N_NODES * 4);
    int*   col       = (int*)take((size_t)N_EDGES * 4);
    unsigned short* Abf = (unsigned short*)take((size_t)N_NODES * IN_F * 2);
    unsigned short* Wt0 = (unsigned short*)take((size_t)IN_F * HID * 2);
    unsigned short* Wt1 = (unsigned short*)take((size_t)HID * HID * 2);
    unsigned short* Wt2 = (unsigned short*)take((size_t)HID * CLSP * 2);
    unsigned short* h0  = (unsigned short*)take((size_t)N_NODES * HID * 2);
    unsigned short* h1  = (unsigned short*)take((size_t)N_NODES * HID * 2);  // also h2 later
    unsigned short* hb  = (unsigned short*)take((size_t)N_NODES * HID * 2);
    float*          ha  = (float*)take((size_t)N_NODES * HID * 4);
    unsigned short* hc  = (unsigned short*)take((size_t)N_NODES * CLS * 2);

    const int NB_E = (N_EDGES + 255) / 256;
    const int NB_N = (N_NODES + 255) / 256;
    const int NB_M64 = (N_NODES + 63) / 64;
    const int NB_WAVE = (N_NODES * 64 + 255) / 256;

    hipMemsetAsync(deg_out_i, 0, (size_t)N_NODES * 4, stream);
    hipMemsetAsync(deg_in_i, 0, (size_t)N_NODES * 4, stream);
    hipMemsetAsync(cnt, 0, (size_t)N_NODES * 4, stream);

    k_deg<<<NB_E, 256, 0, stream>>>(src, dst, deg_out_i, deg_in_i);
    k_rsqrt<<<NB_N, 256, 0, stream>>>(deg_out_i, deg_in_i, do_is, di_is);

    k_scanA<<<NB_N, 256, 0, stream>>>(deg_in_i, tmp, bsum);
    k_scanB<<<1, 1, 0, stream>>>(bsum, boff, NB_N);
    k_scanC<<<NB_N, 256, 0, stream>>>(tmp, deg_in_i, boff, row_ptr);
    k_fill<<<NB_E, 256, 0, stream>>>(src, dst, row_ptr, cnt, col);

    k_lncvt<<<NB_WAVE, 256, 0, stream>>>(feat, g_in, b_in, Abf);
    k_cvtWT<<<(IN_F * HID + 255) / 256, 256, 0, stream>>>(W0, Wt0, IN_F, HID, HID);
    k_cvtWT<<<(HID * HID + 255) / 256, 256, 0, stream>>>(W1, Wt1, HID, HID, HID);
    k_cvtWT<<<(HID * CLSP + 255) / 256, 256, 0, stream>>>(W2, Wt2, HID, CLS, CLSP);

    // Layer 0
    k_gemm1_mfma<<<NB_M64, 256, 0, stream>>>(Abf, Wt0, do_is, h0);
    k_aggln<<<NB_WAVE, 256, 0, stream>>>(h0, row_ptr, col, di_is, do_is, g0, b0, (unsigned*)h1);

    // Layer 1
    k_agg128b<<<NB_WAVE, 256, 0, stream>>>(h1, row_ptr, col, (unsigned*)hb);
    k_gemm2_mfma<<<NB_M64, 256, 0, stream>>>(hb, Wt1, di_is, ha);
    k_ln128f<<<NB_WAVE, 256, 0, stream>>>(ha, g1, b1, do_is, (unsigned*)h1);

    // Layer 2
    k_gemm3_mfma<<<NB_M64, 256, 0, stream>>>(h1, Wt2, hc);
    k_agg40b<<<NB_WAVE, 256, 0, stream>>>(hc, row_ptr, col, di_is, b2, out);
}